// Round 1
// baseline (1152.824 us; speedup 1.0000x reference)
//
#include <hip/hip_runtime.h>
#include <hip/hip_bf16.h>

// A=128 cells, B=128 regions/minibatch, C=512 in, D=512 out, R=1000
// out[a,b,d] = sum_c x[a,b,c] * w[r_b,c,d] + bias[r_b,d]
// Per-b GEMM: M=128 (a), K=512 (c), N=512 (d). bf16 MFMA, fp32 accumulate.

typedef __bf16 bf16x8 __attribute__((ext_vector_type(8)));
typedef float floatx4 __attribute__((ext_vector_type(4)));

#define LDS_STRIDE 56  // shorts per row (112B): b128 frag reads bank-uniform

__device__ __forceinline__ unsigned int f2bf1(float f) {
  unsigned int u = __float_as_uint(f);
  return (u + 0x7fffu + ((u >> 16) & 1u)) >> 16;  // RNE
}
__device__ __forceinline__ unsigned int f2bf_pack(float lo, float hi) {
  return f2bf1(lo) | (f2bf1(hi) << 16);
}

__global__ __launch_bounds__(256, 2) void le_kernel(
    const float* __restrict__ x, const int* __restrict__ region_ix,
    const float* __restrict__ weight, const float* __restrict__ bias,
    float* __restrict__ out) {
  __shared__ unsigned short As[128 * LDS_STRIDE];  // A[m][k] bf16, k-contig
  __shared__ unsigned short Bs[128 * LDS_STRIDE];  // BT[n][k] bf16, k-contig (block-swizzled)

  const int t = threadIdx.x;
  const int bIdx = blockIdx.y;        // region/minibatch index b
  const int n0 = blockIdx.x * 128;    // N-tile origin in d
  const int r = region_ix[bIdx];

  const float* xp = x + (size_t)bIdx * 512;                 // x[a][b][.]: row a at +a*65536
  const float* wp = weight + (size_t)r * 262144 + n0;       // w[r][c][.]: row c at +c*512

  // ---- staging assignments ----
  // A: thread t loads 16 floats of x row a=t/2, k-half h=t&1 (4 float4)
  const int a_row = t >> 1;
  const int h = t & 1;
  const float* aBase = xp + (size_t)a_row * 65536 + 16 * h;
  // B: thread t loads rows kk=2*(t>>4), kk+1; n-range ns..ns+7, ns=8*(t&15)
  const int kk = 2 * (t >> 4);
  const int ns = 8 * (t & 15);
  const float* bBase = wp + (size_t)kk * 512 + ns;
  const int blk = kk >> 3;        // b128-block index of this k-pair
  const int wo  = (kk >> 1) & 3;  // granule offset within block

  // ---- wave/lane mapping (2x2 waves, each 64x64 = 4x4 MFMA tiles) ----
  const int lane = t & 63;
  const int wave = t >> 6;
  const int wm = (wave & 1) * 64;
  const int wn = (wave >> 1) * 64;
  const int lm = lane & 15;
  const int lk = lane >> 4;

  floatx4 acc[4][4];
#pragma unroll
  for (int i = 0; i < 4; ++i)
#pragma unroll
    for (int j = 0; j < 4; ++j) acc[i][j] = (floatx4){0.f, 0.f, 0.f, 0.f};

  float4 aL[4], bL[4];
  {  // prologue: loads for k0 = 0
    const float4* ap = (const float4*)aBase;
    aL[0] = ap[0]; aL[1] = ap[1]; aL[2] = ap[2]; aL[3] = ap[3];
    const float4* bp0 = (const float4*)bBase;
    const float4* bp1 = (const float4*)(bBase + 512);
    bL[0] = bp0[0]; bL[1] = bp0[1];
    bL[2] = bp1[0]; bL[3] = bp1[1];
  }

#pragma unroll 1
  for (int kt = 0; kt < 16; ++kt) {
    if (kt) __syncthreads();  // previous compute phase done before overwriting LDS

    // ---- stage A: 16 bf16 at As[a_row][16h..16h+15] (two b128 writes) ----
    {
      uint4 p0, p1;
      p0.x = f2bf_pack(aL[0].x, aL[0].y); p0.y = f2bf_pack(aL[0].z, aL[0].w);
      p0.z = f2bf_pack(aL[1].x, aL[1].y); p0.w = f2bf_pack(aL[1].z, aL[1].w);
      p1.x = f2bf_pack(aL[2].x, aL[2].y); p1.y = f2bf_pack(aL[2].z, aL[2].w);
      p1.z = f2bf_pack(aL[3].x, aL[3].y); p1.w = f2bf_pack(aL[3].z, aL[3].w);
      uint4* dst = (uint4*)&As[a_row * LDS_STRIDE + 16 * h];
      dst[0] = p0; dst[1] = p1;
    }
    // ---- stage B transposed: granule (n, kk/2) = (w[kk][n], w[kk+1][n]) ----
    {
      unsigned int g0 = f2bf_pack(bL[0].x, bL[2].x);
      unsigned int g1 = f2bf_pack(bL[0].y, bL[2].y);
      unsigned int g2 = f2bf_pack(bL[0].z, bL[2].z);
      unsigned int g3 = f2bf_pack(bL[0].w, bL[2].w);
      unsigned int g4 = f2bf_pack(bL[1].x, bL[3].x);
      unsigned int g5 = f2bf_pack(bL[1].y, bL[3].y);
      unsigned int g6 = f2bf_pack(bL[1].z, bL[3].z);
      unsigned int g7 = f2bf_pack(bL[1].w, bL[3].w);
      // slot s = 4*(blk ^ ((n>>3)&3)) + wo ; (n>>3)&3 == (t&3) for all 8 n's here
      const int s2 = 2 * (4 * (blk ^ (t & 3)) + wo);  // short offset within row
#pragma unroll
      for (int i = 0; i < 8; ++i) {
        unsigned int gv = (i == 0) ? g0 : (i == 1) ? g1 : (i == 2) ? g2 : (i == 3) ? g3
                        : (i == 4) ? g4 : (i == 5) ? g5 : (i == 6) ? g6 : g7;
        *(unsigned int*)&Bs[(ns + i) * LDS_STRIDE + s2] = gv;
      }
    }
    __syncthreads();

    // ---- prefetch next K-tile into registers (overlaps MFMA phase) ----
    if (kt < 15) {
      const int k0 = (kt + 1) * 32;
      const float4* ap = (const float4*)(aBase + k0);
      aL[0] = ap[0]; aL[1] = ap[1]; aL[2] = ap[2]; aL[3] = ap[3];
      const float4* bp0 = (const float4*)(bBase + (size_t)k0 * 512);
      const float4* bp1 = (const float4*)(bBase + (size_t)k0 * 512 + 512);
      bL[0] = bp0[0]; bL[1] = bp0[1];
      bL[2] = bp1[0]; bL[3] = bp1[1];
    }

    // ---- compute: 4 A-frags, 4 B-frags, 16 MFMAs ----
    bf16x8 afr[4], bfr[4];
#pragma unroll
    for (int tm = 0; tm < 4; ++tm)
      afr[tm] = *(const bf16x8*)&As[(wm + 16 * tm + lm) * LDS_STRIDE + 8 * lk];
#pragma unroll
    for (int tn = 0; tn < 4; ++tn) {
      const int n = wn + 16 * tn + lm;
      const int sb = lk ^ ((n >> 3) & 3);  // un-swizzle block
      bfr[tn] = *(const bf16x8*)&Bs[n * LDS_STRIDE + 8 * sb];
    }
#pragma unroll
    for (int tm = 0; tm < 4; ++tm)
#pragma unroll
      for (int tn = 0; tn < 4; ++tn)
        acc[tm][tn] = __builtin_amdgcn_mfma_f32_16x16x32_bf16(
            afr[tm], bfr[tn], acc[tm][tn], 0, 0, 0);
  }

  // ---- epilogue: add bias, store fp32 ----
  float bv[4];
#pragma unroll
  for (int tn = 0; tn < 4; ++tn)
    bv[tn] = bias[(size_t)r * 512 + n0 + wn + 16 * tn + lm];

#pragma unroll
  for (int tm = 0; tm < 4; ++tm) {
#pragma unroll
    for (int tn = 0; tn < 4; ++tn) {
      const int d = n0 + wn + 16 * tn + lm;
#pragma unroll
      for (int v = 0; v < 4; ++v) {
        const int arow = wm + 16 * tm + 4 * lk + v;  // C/D: col=lane&15, row=(lane>>4)*4+reg
        out[(size_t)arow * 65536 + (size_t)bIdx * 512 + d] = acc[tm][tn][v] + bv[tn];
      }
    }
  }
}

extern "C" void kernel_launch(void* const* d_in, const int* in_sizes, int n_in,
                              void* d_out, int out_size, void* d_ws, size_t ws_size,
                              hipStream_t stream) {
  (void)in_sizes; (void)n_in; (void)out_size; (void)d_ws; (void)ws_size;
  const float* x = (const float*)d_in[0];
  const int* region_ix = (const int*)d_in[1];
  const float* weight = (const float*)d_in[2];
  const float* bias = (const float*)d_in[3];
  float* out = (float*)d_out;

  dim3 grid(4, 128);   // 4 N-tiles x 128 b -> 512 WGs (2/CU)
  dim3 block(256);
  le_kernel<<<grid, block, 0, stream>>>(x, region_ix, weight, bias, out);
}